// Round 3
// baseline (280.676 us; speedup 1.0000x reference)
//
#include <hip/hip_runtime.h>
#include <hip/hip_bf16.h>
#include <cstdint>

// Problem constants
#define B_    2
#define S_    2048
#define H_    512
#define N_    8
#define D_    64
#define BS_   4096      // B*S
#define ND_   512       // N*D
#define CHUNK 64
#define NCH   32        // S_/CHUNK
#define NBN   16        // B*N
#define EPS_  1e-6f

// ---------------------------------------------------------------------------
// Shared tiled-GEMM body: [4096,512] x [512,512] + bias, optional phi=elu+1.
// BM=128, BN=64, BK=16, 256 threads, 8x4 micro-tile per thread.
// ---------------------------------------------------------------------------
__device__ __forceinline__ void gemm512_body(const float* __restrict__ X,
                                             const float* __restrict__ W,
                                             const float* __restrict__ bias,
                                             float* __restrict__ O,
                                             bool phi)
{
    __shared__ float As[16][132];   // [k][m]
    __shared__ float Bs[16][68];    // [k][n]

    const int tid = threadIdx.x;
    const int tx  = tid & 15;       // col group (4 cols)
    const int ty  = tid >> 4;       // row group (8 rows)
    const int row0 = blockIdx.y * 128;
    const int col0 = blockIdx.x * 64;

    float acc[8][4];
#pragma unroll
    for (int u = 0; u < 8; u++)
#pragma unroll
        for (int v = 0; v < 4; v++) acc[u][v] = 0.f;

    for (int k0 = 0; k0 < 512; k0 += 16) {
#pragma unroll
        for (int i = 0; i < 8; i++) {
            int r  = (tid >> 4) + i * 16;     // 0..127
            int kc = tid & 15;                // 0..15
            As[kc][r] = X[(size_t)(row0 + r) * 512 + k0 + kc];
        }
#pragma unroll
        for (int i = 0; i < 4; i++) {
            int kr = (tid >> 6) + i * 4;      // 0..15
            int cc = tid & 63;                // 0..63
            Bs[kr][cc] = W[(size_t)(k0 + kr) * 512 + col0 + cc];
        }
        __syncthreads();
#pragma unroll
        for (int kk = 0; kk < 16; kk++) {
            float a[8], b[4];
#pragma unroll
            for (int u = 0; u < 8; u++) a[u] = As[kk][ty * 8 + u];
#pragma unroll
            for (int v = 0; v < 4; v++) b[v] = Bs[kk][tx * 4 + v];
#pragma unroll
            for (int u = 0; u < 8; u++)
#pragma unroll
                for (int v = 0; v < 4; v++)
                    acc[u][v] += a[u] * b[v];
        }
        __syncthreads();
    }

#pragma unroll
    for (int u = 0; u < 8; u++) {
        int r = row0 + ty * 8 + u;
#pragma unroll
        for (int v = 0; v < 4; v++) {
            int c = col0 + tx * 4 + v;
            float val = acc[u][v] + bias[c];
            if (phi) val = (val > 0.f) ? (val + 1.f) : __expf(val);  // elu(x)+1
            O[(size_t)r * 512 + c] = val;
        }
    }
}

// K1: fused QKV projections. grid (8, 32, 3), block 256
__global__ __launch_bounds__(256) void qkv_proj_kernel(
    const float* __restrict__ q_in, const float* __restrict__ k_in, const float* __restrict__ v_in,
    const float* __restrict__ wq, const float* __restrict__ wk, const float* __restrict__ wv,
    const float* __restrict__ bq, const float* __restrict__ bk, const float* __restrict__ bv,
    float* __restrict__ pq, float* __restrict__ pk, float* __restrict__ pv)
{
    int m = blockIdx.z;
    const float* X  = (m == 0) ? q_in : (m == 1) ? k_in : v_in;
    const float* W  = (m == 0) ? wq   : (m == 1) ? wk   : wv;
    const float* Bb = (m == 0) ? bq   : (m == 1) ? bk   : bv;
    float*       O  = (m == 0) ? pq   : (m == 1) ? pk   : pv;
    gemm512_body(X, W, Bb, O, m < 2);
}

// K5: output projection. grid (8, 32), block 256
__global__ __launch_bounds__(256) void out_proj_kernel(
    const float* __restrict__ av, const float* __restrict__ wo,
    const float* __restrict__ bo, float* __restrict__ out)
{
    gemm512_body(av, wo, bo, out, false);
}

// ---------------------------------------------------------------------------
// K2: per-chunk partials  M_c[h,d] = sum_t phiK[t,h]*V[t,d],  z_c[h] = sum_t phiK[t,h]
// grid (NCH=32, NBN=16), block 256
// ---------------------------------------------------------------------------
__global__ __launch_bounds__(256) void chunk_kv_kernel(
    const float* __restrict__ pk, const float* __restrict__ pv,
    float* __restrict__ Mb, float* __restrict__ zb)
{
    __shared__ float Ks[16][65];
    __shared__ float Vs[16][65];
    const int c  = blockIdx.x;
    const int bn = blockIdx.y;
    const int b  = bn >> 3, n = bn & 7;
    const int row0 = b * S_ + c * CHUNK;
    const int col0 = n * 64;
    const int tid = threadIdx.x;
    const int tx = tid & 15, ty = tid >> 4;

    float acc[4][4];
#pragma unroll
    for (int i = 0; i < 4; i++)
#pragma unroll
        for (int j = 0; j < 4; j++) acc[i][j] = 0.f;
    float zacc = 0.f;

    for (int t0 = 0; t0 < CHUNK; t0 += 16) {
#pragma unroll
        for (int i = 0; i < 4; i++) {
            int t  = (tid >> 6) + i * 4;      // 0..15
            int cc = tid & 63;
            size_t g = (size_t)(row0 + t0 + t) * 512 + col0 + cc;
            Ks[t][cc] = pk[g];
            Vs[t][cc] = pv[g];
        }
        __syncthreads();
#pragma unroll
        for (int t = 0; t < 16; t++) {
            float a[4], bb[4];
#pragma unroll
            for (int i = 0; i < 4; i++) a[i]  = Ks[t][ty * 4 + i];
#pragma unroll
            for (int j = 0; j < 4; j++) bb[j] = Vs[t][tx * 4 + j];
#pragma unroll
            for (int i = 0; i < 4; i++)
#pragma unroll
                for (int j = 0; j < 4; j++) acc[i][j] += a[i] * bb[j];
        }
        if (tid < 64) {
#pragma unroll
            for (int t = 0; t < 16; t++) zacc += Ks[t][tid];
        }
        __syncthreads();
    }

    size_t mbase = ((size_t)bn * NCH + c) * 4096;
#pragma unroll
    for (int i = 0; i < 4; i++)
#pragma unroll
        for (int j = 0; j < 4; j++)
            Mb[mbase + (size_t)(ty * 4 + i) * 64 + tx * 4 + j] = acc[i][j];
    if (tid < 64) zb[((size_t)bn * NCH + c) * 64 + tid] = zacc;
}

// ---------------------------------------------------------------------------
// K3: exclusive prefix scan over chunks (in place).
// grid (17, 16): x<16 -> M slices (256 elems each), x==16 -> z
// ---------------------------------------------------------------------------
__global__ __launch_bounds__(256) void scan_kernel(float* __restrict__ Mb,
                                                   float* __restrict__ zb)
{
    const int bn  = blockIdx.y;
    const int tid = threadIdx.x;
    if (blockIdx.x < 16) {
        const int e = blockIdx.x * 256 + tid;   // 0..4095
        float run = 0.f;
        for (int c = 0; c < NCH; c++) {
            size_t idx = ((size_t)bn * NCH + c) * 4096 + e;
            float t = Mb[idx];
            Mb[idx] = run;
            run += t;
        }
    } else if (tid < 64) {
        float run = 0.f;
        for (int c = 0; c < NCH; c++) {
            size_t idx = ((size_t)bn * NCH + c) * 64 + tid;
            float t = zb[idx];
            zb[idx] = run;
            run += t;
        }
    }
}

// ---------------------------------------------------------------------------
// K4: per-chunk attention output.
//   A[s,t] = (t<=s) ? phiQ[s]·phiK[t] : 0
//   O[s,d] = A@V + phiQ@S_prev ;  denom[s] = phiQ[s]·z_prev + rowsum(A) + eps
//   av_scrambled store replicating the reference's (bn,s,d)->(b,s,n,d) reshape:
//   true element (b, n, s_b, d) -> row b*2048 + ((n*2048+s_b)>>3),
//                                  col ((n*2048+s_b)&7)*64 + d
// grid (NCH=32, NBN=16), block 256
// ---------------------------------------------------------------------------
__global__ __launch_bounds__(256) void chunk_attn_kernel(
    const float* __restrict__ pq, const float* __restrict__ pk,
    const float* __restrict__ pv, const float* __restrict__ Mb,
    const float* __restrict__ zb, float* __restrict__ av)
{
    const int PAD = 65;
    __shared__ float Pq[64 * 65];
    __shared__ float Pk[64 * 65];
    __shared__ float Vv[64 * 65];
    __shared__ float Sp[64 * 65];
    __shared__ float Aa[64 * 65];
    __shared__ float zp[64];
    __shared__ float denom[64];

    const int c  = blockIdx.x;
    const int bn = blockIdx.y;
    const int b  = bn >> 3, n = bn & 7;
    const int row0 = b * S_ + c * CHUNK;
    const int col0 = n * 64;
    const int tid = threadIdx.x;
    const int tx = tid & 15, ty = tid >> 4;
    const size_t mbase = ((size_t)bn * NCH + c) * 4096;

#pragma unroll
    for (int i = 0; i < 16; i++) {
        int r  = (tid >> 6) + i * 4;          // 0..63
        int cc = tid & 63;
        size_t g = (size_t)(row0 + r) * 512 + col0 + cc;
        Pq[r * PAD + cc] = pq[g];
        Pk[r * PAD + cc] = pk[g];
        Vv[r * PAD + cc] = pv[g];
        Sp[r * PAD + cc] = Mb[mbase + (size_t)r * 64 + cc];
    }
    if (tid < 64) zp[tid] = zb[((size_t)bn * NCH + c) * 64 + tid];
    __syncthreads();

    // Phase 2: A = phiQ @ phiK^T, causal-masked
    {
        float acc[4][4];
#pragma unroll
        for (int i = 0; i < 4; i++)
#pragma unroll
            for (int j = 0; j < 4; j++) acc[i][j] = 0.f;
        for (int h = 0; h < 64; h++) {
            float a[4], bb[4];
#pragma unroll
            for (int i = 0; i < 4; i++) a[i]  = Pq[(ty * 4 + i) * PAD + h];
#pragma unroll
            for (int j = 0; j < 4; j++) bb[j] = Pk[(tx * 4 + j) * PAD + h];
#pragma unroll
            for (int i = 0; i < 4; i++)
#pragma unroll
                for (int j = 0; j < 4; j++) acc[i][j] += a[i] * bb[j];
        }
#pragma unroll
        for (int i = 0; i < 4; i++)
#pragma unroll
            for (int j = 0; j < 4; j++) {
                int s = ty * 4 + i, t = tx * 4 + j;
                Aa[s * PAD + t] = (t <= s) ? acc[i][j] : 0.f;
            }
    }
    __syncthreads();

    // denominators (64 threads)
    if (tid < 64) {
        float dsum = 0.f;
        for (int h = 0; h < 64; h++) dsum += Pq[tid * PAD + h] * zp[h];
        for (int t = 0; t < 64; t++) dsum += Aa[tid * PAD + t];
        denom[tid] = dsum + EPS_;
    }

    // Phase 3: O = A@V + phiQ@S_prev
    float o[4][4];
#pragma unroll
    for (int i = 0; i < 4; i++)
#pragma unroll
        for (int j = 0; j < 4; j++) o[i][j] = 0.f;
    for (int t = 0; t < 64; t++) {
        float a[4], bb[4];
#pragma unroll
        for (int i = 0; i < 4; i++) a[i]  = Aa[(ty * 4 + i) * PAD + t];
#pragma unroll
        for (int j = 0; j < 4; j++) bb[j] = Vv[t * PAD + tx * 4 + j];
#pragma unroll
        for (int i = 0; i < 4; i++)
#pragma unroll
            for (int j = 0; j < 4; j++) o[i][j] += a[i] * bb[j];
    }
    for (int h = 0; h < 64; h++) {
        float a[4], bb[4];
#pragma unroll
        for (int i = 0; i < 4; i++) a[i]  = Pq[(ty * 4 + i) * PAD + h];
#pragma unroll
        for (int j = 0; j < 4; j++) bb[j] = Sp[h * PAD + tx * 4 + j];
#pragma unroll
        for (int i = 0; i < 4; i++)
#pragma unroll
            for (int j = 0; j < 4; j++) o[i][j] += a[i] * bb[j];
    }
    __syncthreads();   // denom visible to all

    // Scrambled store (replicates reference reshape quirk)
#pragma unroll
    for (int i = 0; i < 4; i++) {
        int s_loc = ty * 4 + i;
        int s_b   = c * CHUNK + s_loc;        // time index within batch
        int jj    = n * S_ + s_b;             // n*2048 + s
        int s2    = jj >> 3;
        int n2    = jj & 7;
        float inv = 1.f / denom[s_loc];
        size_t obase = (size_t)(b * S_ + s2) * 512 + (size_t)n2 * 64;
#pragma unroll
        for (int v = 0; v < 4; v++)
            av[obase + tx * 4 + v] = o[i][v] * inv;
    }
}

// ---------------------------------------------------------------------------
extern "C" void kernel_launch(void* const* d_in, const int* in_sizes, int n_in,
                              void* d_out, int out_size, void* d_ws, size_t ws_size,
                              hipStream_t stream)
{
    const float* q_in = (const float*)d_in[0];
    const float* k_in = (const float*)d_in[1];
    const float* v_in = (const float*)d_in[2];
    const float* wq   = (const float*)d_in[3];
    const float* bq   = (const float*)d_in[4];
    const float* wk   = (const float*)d_in[5];
    const float* bk   = (const float*)d_in[6];
    const float* wv   = (const float*)d_in[7];
    const float* bv   = (const float*)d_in[8];
    const float* wo   = (const float*)d_in[9];
    const float* bo   = (const float*)d_in[10];
    float* out = (float*)d_out;

    float* ws = (float*)d_ws;
    const size_t PLANE = (size_t)BS_ * ND_;   // 2097152
    float* pq   = ws;
    float* pk   = pq + PLANE;
    float* pv   = pk + PLANE;
    float* av   = pv + PLANE;
    float* Mb   = av + PLANE;                 // NBN*NCH*4096 = 2097152
    float* zb   = Mb + PLANE;                 // NBN*NCH*64   = 32768

    qkv_proj_kernel<<<dim3(8, 32, 3), 256, 0, stream>>>(
        q_in, k_in, v_in, wq, wk, wv, bq, bk, bv, pq, pk, pv);
    chunk_kv_kernel<<<dim3(NCH, NBN), 256, 0, stream>>>(pk, pv, Mb, zb);
    scan_kernel<<<dim3(17, NBN), 256, 0, stream>>>(Mb, zb);
    chunk_attn_kernel<<<dim3(NCH, NBN), 256, 0, stream>>>(pq, pk, pv, Mb, zb, av);
    out_proj_kernel<<<dim3(8, 32), 256, 0, stream>>>(av, wo, bo, out);
}

// Round 4
// 184.805 us; speedup vs baseline: 1.5188x; 1.5188x over previous
//
#include <hip/hip_runtime.h>
#include <hip/hip_bf16.h>
#include <cstdint>

// Problem constants
#define B_    2
#define S_    2048
#define H_    512
#define N_    8
#define D_    64
#define BS_   4096      // B*S
#define ND_   512       // N*D
#define CHUNK 64
#define NCH   32        // S_/CHUNK
#define NBN   16        // B*N
#define EPS_  1e-6f

typedef __attribute__((ext_vector_type(4))) float  f32x4;
typedef __attribute__((ext_vector_type(8))) short  short8;

static __device__ __forceinline__ unsigned short f2bf(float x) {
    __hip_bfloat16 h = __float2bfloat16(x);
    return *reinterpret_cast<unsigned short*>(&h);
}

// ---------------------------------------------------------------------------
// K0a: activations f32 -> bf16.  grid (1024, 3), block 256, 8 elems/thread
// ---------------------------------------------------------------------------
__global__ __launch_bounds__(256) void convert_act_kernel(
    const float* __restrict__ q, const float* __restrict__ k, const float* __restrict__ v,
    unsigned short* __restrict__ qb, unsigned short* __restrict__ kb, unsigned short* __restrict__ vb)
{
    const int p = blockIdx.y;
    const float* src = (p == 0) ? q : (p == 1) ? k : v;
    unsigned short* dst = (p == 0) ? qb : (p == 1) ? kb : vb;
    size_t idx = ((size_t)blockIdx.x * 256 + threadIdx.x) * 8;
    float4 a = *reinterpret_cast<const float4*>(src + idx);
    float4 b = *reinterpret_cast<const float4*>(src + idx + 4);
    short8 o;
    o[0] = (short)f2bf(a.x); o[1] = (short)f2bf(a.y);
    o[2] = (short)f2bf(a.z); o[3] = (short)f2bf(a.w);
    o[4] = (short)f2bf(b.x); o[5] = (short)f2bf(b.y);
    o[6] = (short)f2bf(b.z); o[7] = (short)f2bf(b.w);
    *reinterpret_cast<short8*>(dst + idx) = o;
}

// ---------------------------------------------------------------------------
// K0b: weight transpose+convert: Wt[c][k] = bf16(W[k][c]).  W is [512][512].
// grid (8, 8, 4), block 256, 64x64 tiles via LDS.
// ---------------------------------------------------------------------------
__global__ __launch_bounds__(256) void convert_wt_kernel(
    const float* __restrict__ wq, const float* __restrict__ wk,
    const float* __restrict__ wv, const float* __restrict__ wo,
    unsigned short* __restrict__ wqt, unsigned short* __restrict__ wkt,
    unsigned short* __restrict__ wvt, unsigned short* __restrict__ wot)
{
    const int m = blockIdx.z;
    const float* W = (m == 0) ? wq : (m == 1) ? wk : (m == 2) ? wv : wo;
    unsigned short* Wt = (m == 0) ? wqt : (m == 1) ? wkt : (m == 2) ? wvt : wot;

    __shared__ float t[64][65];
    const int k0 = blockIdx.y * 64, c0 = blockIdx.x * 64;
    const int tid = threadIdx.x;
    const int rr = tid >> 6;       // 0..3
    const int cc = tid & 63;
#pragma unroll
    for (int p = 0; p < 16; p++) {
        int kl = rr + p * 4;
        t[kl][cc] = W[(size_t)(k0 + kl) * 512 + c0 + cc];
    }
    __syncthreads();
#pragma unroll
    for (int p = 0; p < 16; p++) {
        int cl = rr + p * 4;
        Wt[(size_t)(c0 + cl) * 512 + k0 + cc] = f2bf(t[cc][cl]);
    }
}

// ---------------------------------------------------------------------------
// MFMA GEMM body: [4096,512](bf16) x Wt[512,512](bf16, pre-transposed) ->
// [4096,512](f32), + bias, optional phi.  128x128 tile, BK=64, 256 thr (4 waves),
// each wave computes 64x64 via 4x4 fragments of 16x16x32.
// ---------------------------------------------------------------------------
__device__ __forceinline__ void mfma_gemm_body(
    const unsigned short* __restrict__ X, const unsigned short* __restrict__ Wt,
    const float* __restrict__ bias, float* __restrict__ O, bool phi)
{
    __shared__ unsigned short As[128][72];   // +8 pad: rows stride 144B -> 2-way banks (free)
    __shared__ unsigned short Bs[128][72];

    const int tid  = threadIdx.x;
    const int lane = tid & 63;
    const int w    = tid >> 6;               // wave 0..3
    const int wm   = (w & 1) * 64;
    const int wn   = (w >> 1) * 64;
    const int row0 = blockIdx.y * 128;
    const int col0 = blockIdx.x * 128;
    const int frow = lane & 15;
    const int fk   = (lane >> 4) * 8;

    f32x4 acc[4][4];
#pragma unroll
    for (int m = 0; m < 4; m++)
#pragma unroll
        for (int n = 0; n < 4; n++) acc[m][n] = (f32x4){0.f, 0.f, 0.f, 0.f};

    const int lr = tid >> 3;                 // 0..31
    const int lc = (tid & 7) * 8;            // 0..56

    for (int k0 = 0; k0 < 512; k0 += 64) {
#pragma unroll
        for (int p = 0; p < 4; p++) {
            int r = lr + p * 32;
            *reinterpret_cast<short8*>(&As[r][lc]) =
                *reinterpret_cast<const short8*>(X + (size_t)(row0 + r) * 512 + k0 + lc);
            *reinterpret_cast<short8*>(&Bs[r][lc]) =
                *reinterpret_cast<const short8*>(Wt + (size_t)(col0 + r) * 512 + k0 + lc);
        }
        __syncthreads();
#pragma unroll
        for (int kk = 0; kk < 64; kk += 32) {
            short8 a[4], b[4];
#pragma unroll
            for (int m = 0; m < 4; m++)
                a[m] = *reinterpret_cast<const short8*>(&As[wm + m * 16 + frow][kk + fk]);
#pragma unroll
            for (int n = 0; n < 4; n++)
                b[n] = *reinterpret_cast<const short8*>(&Bs[wn + n * 16 + frow][kk + fk]);
#pragma unroll
            for (int m = 0; m < 4; m++)
#pragma unroll
                for (int n = 0; n < 4; n++)
                    acc[m][n] = __builtin_amdgcn_mfma_f32_16x16x32_bf16(
                        a[m], b[n], acc[m][n], 0, 0, 0);
        }
        __syncthreads();
    }

    // Epilogue: C/D layout col=lane&15, row=(lane>>4)*4+reg (m89-verified)
#pragma unroll
    for (int n = 0; n < 4; n++) {
        int col = col0 + wn + n * 16 + frow;
        float bv_ = bias[col];
#pragma unroll
        for (int m = 0; m < 4; m++) {
#pragma unroll
            for (int r = 0; r < 4; r++) {
                int row = row0 + wm + m * 16 + (lane >> 4) * 4 + r;
                float val = acc[m][n][r] + bv_;
                if (phi) val = (val > 0.f) ? (val + 1.f) : __expf(val);
                O[(size_t)row * 512 + col] = val;
            }
        }
    }
}

// K1: QKV projections (MFMA). grid (4, 32, 3), block 256
__global__ __launch_bounds__(256) void qkv_proj_kernel(
    const unsigned short* __restrict__ qb, const unsigned short* __restrict__ kb,
    const unsigned short* __restrict__ vb,
    const unsigned short* __restrict__ wqt, const unsigned short* __restrict__ wkt,
    const unsigned short* __restrict__ wvt,
    const float* __restrict__ bq, const float* __restrict__ bk, const float* __restrict__ bv,
    float* __restrict__ pq, float* __restrict__ pk, float* __restrict__ pv)
{
    int m = blockIdx.z;
    const unsigned short* X  = (m == 0) ? qb  : (m == 1) ? kb  : vb;
    const unsigned short* Wt = (m == 0) ? wqt : (m == 1) ? wkt : wvt;
    const float* Bb          = (m == 0) ? bq  : (m == 1) ? bk  : bv;
    float* O                 = (m == 0) ? pq  : (m == 1) ? pk  : pv;
    mfma_gemm_body(X, Wt, Bb, O, m < 2);
}

// K5: output projection (MFMA). grid (4, 32), block 256
__global__ __launch_bounds__(256) void out_proj_kernel(
    const unsigned short* __restrict__ avb, const unsigned short* __restrict__ wot,
    const float* __restrict__ bo, float* __restrict__ out)
{
    mfma_gemm_body(avb, wot, bo, out, false);
}

// ---------------------------------------------------------------------------
// K2: per-chunk partials  M_c[h,d] = sum_t phiK[t,h]*V[t,d],  z_c[h] = sum_t phiK[t,h]
// grid (NCH=32, NBN=16), block 256
// ---------------------------------------------------------------------------
__global__ __launch_bounds__(256) void chunk_kv_kernel(
    const float* __restrict__ pk, const float* __restrict__ pv,
    float* __restrict__ Mb, float* __restrict__ zb)
{
    __shared__ float Ks[16][65];
    __shared__ float Vs[16][65];
    const int c  = blockIdx.x;
    const int bn = blockIdx.y;
    const int b  = bn >> 3, n = bn & 7;
    const int row0 = b * S_ + c * CHUNK;
    const int col0 = n * 64;
    const int tid = threadIdx.x;
    const int tx = tid & 15, ty = tid >> 4;

    float acc[4][4];
#pragma unroll
    for (int i = 0; i < 4; i++)
#pragma unroll
        for (int j = 0; j < 4; j++) acc[i][j] = 0.f;
    float zacc = 0.f;

    for (int t0 = 0; t0 < CHUNK; t0 += 16) {
#pragma unroll
        for (int i = 0; i < 4; i++) {
            int t  = (tid >> 6) + i * 4;
            int cc = tid & 63;
            size_t g = (size_t)(row0 + t0 + t) * 512 + col0 + cc;
            Ks[t][cc] = pk[g];
            Vs[t][cc] = pv[g];
        }
        __syncthreads();
#pragma unroll
        for (int t = 0; t < 16; t++) {
            float a[4], bb[4];
#pragma unroll
            for (int i = 0; i < 4; i++) a[i]  = Ks[t][ty * 4 + i];
#pragma unroll
            for (int j = 0; j < 4; j++) bb[j] = Vs[t][tx * 4 + j];
#pragma unroll
            for (int i = 0; i < 4; i++)
#pragma unroll
                for (int j = 0; j < 4; j++) acc[i][j] += a[i] * bb[j];
        }
        if (tid < 64) {
#pragma unroll
            for (int t = 0; t < 16; t++) zacc += Ks[t][tid];
        }
        __syncthreads();
    }

    size_t mbase = ((size_t)bn * NCH + c) * 4096;
#pragma unroll
    for (int i = 0; i < 4; i++)
#pragma unroll
        for (int j = 0; j < 4; j++)
            Mb[mbase + (size_t)(ty * 4 + i) * 64 + tx * 4 + j] = acc[i][j];
    if (tid < 64) zb[((size_t)bn * NCH + c) * 64 + tid] = zacc;
}

// ---------------------------------------------------------------------------
// K3: exclusive prefix scan over chunks (in place).
// ---------------------------------------------------------------------------
__global__ __launch_bounds__(256) void scan_kernel(float* __restrict__ Mb,
                                                   float* __restrict__ zb)
{
    const int bn  = blockIdx.y;
    const int tid = threadIdx.x;
    if (blockIdx.x < 16) {
        const int e = blockIdx.x * 256 + tid;
        float run = 0.f;
        for (int c = 0; c < NCH; c++) {
            size_t idx = ((size_t)bn * NCH + c) * 4096 + e;
            float t = Mb[idx];
            Mb[idx] = run;
            run += t;
        }
    } else if (tid < 64) {
        float run = 0.f;
        for (int c = 0; c < NCH; c++) {
            size_t idx = ((size_t)bn * NCH + c) * 64 + tid;
            float t = zb[idx];
            zb[idx] = run;
            run += t;
        }
    }
}

// ---------------------------------------------------------------------------
// K4: per-chunk attention output; av stored as bf16 in the reference's
// scrambled (bn,s,d)->(b,s,n,d) reshape layout.
// grid (NCH=32, NBN=16), block 256
// ---------------------------------------------------------------------------
__global__ __launch_bounds__(256) void chunk_attn_kernel(
    const float* __restrict__ pq, const float* __restrict__ pk,
    const float* __restrict__ pv, const float* __restrict__ Mb,
    const float* __restrict__ zb, unsigned short* __restrict__ av)
{
    const int PAD = 65;
    __shared__ float Pq[64 * 65];
    __shared__ float Pk[64 * 65];
    __shared__ float Vv[64 * 65];
    __shared__ float Sp[64 * 65];
    __shared__ float Aa[64 * 65];
    __shared__ float zp[64];
    __shared__ float denom[64];

    const int c  = blockIdx.x;
    const int bn = blockIdx.y;
    const int b  = bn >> 3, n = bn & 7;
    const int row0 = b * S_ + c * CHUNK;
    const int col0 = n * 64;
    const int tid = threadIdx.x;
    const int tx = tid & 15, ty = tid >> 4;
    const size_t mbase = ((size_t)bn * NCH + c) * 4096;

#pragma unroll
    for (int i = 0; i < 16; i++) {
        int r  = (tid >> 6) + i * 4;
        int cc = tid & 63;
        size_t g = (size_t)(row0 + r) * 512 + col0 + cc;
        Pq[r * PAD + cc] = pq[g];
        Pk[r * PAD + cc] = pk[g];
        Vv[r * PAD + cc] = pv[g];
        Sp[r * PAD + cc] = Mb[mbase + (size_t)r * 64 + cc];
    }
    if (tid < 64) zp[tid] = zb[((size_t)bn * NCH + c) * 64 + tid];
    __syncthreads();

    // A = phiQ @ phiK^T, causal-masked
    {
        float acc[4][4];
#pragma unroll
        for (int i = 0; i < 4; i++)
#pragma unroll
            for (int j = 0; j < 4; j++) acc[i][j] = 0.f;
        for (int h = 0; h < 64; h++) {
            float a[4], bb[4];
#pragma unroll
            for (int i = 0; i < 4; i++) a[i]  = Pq[(ty * 4 + i) * PAD + h];
#pragma unroll
            for (int j = 0; j < 4; j++) bb[j] = Pk[(tx * 4 + j) * PAD + h];
#pragma unroll
            for (int i = 0; i < 4; i++)
#pragma unroll
                for (int j = 0; j < 4; j++) acc[i][j] += a[i] * bb[j];
        }
#pragma unroll
        for (int i = 0; i < 4; i++)
#pragma unroll
            for (int j = 0; j < 4; j++) {
                int s = ty * 4 + i, t = tx * 4 + j;
                Aa[s * PAD + t] = (t <= s) ? acc[i][j] : 0.f;
            }
    }
    __syncthreads();

    if (tid < 64) {
        float dsum = 0.f;
        for (int h = 0; h < 64; h++) dsum += Pq[tid * PAD + h] * zp[h];
        for (int t = 0; t < 64; t++) dsum += Aa[tid * PAD + t];
        denom[tid] = dsum + EPS_;
    }

    // O = A@V + phiQ@S_prev
    float o[4][4];
#pragma unroll
    for (int i = 0; i < 4; i++)
#pragma unroll
        for (int j = 0; j < 4; j++) o[i][j] = 0.f;
    for (int t = 0; t < 64; t++) {
        float a[4], bb[4];
#pragma unroll
        for (int i = 0; i < 4; i++) a[i]  = Aa[(ty * 4 + i) * PAD + t];
#pragma unroll
        for (int j = 0; j < 4; j++) bb[j] = Vv[t * PAD + tx * 4 + j];
#pragma unroll
        for (int i = 0; i < 4; i++)
#pragma unroll
            for (int j = 0; j < 4; j++) o[i][j] += a[i] * bb[j];
    }
    for (int h = 0; h < 64; h++) {
        float a[4], bb[4];
#pragma unroll
        for (int i = 0; i < 4; i++) a[i]  = Pq[(ty * 4 + i) * PAD + h];
#pragma unroll
        for (int j = 0; j < 4; j++) bb[j] = Sp[h * PAD + tx * 4 + j];
#pragma unroll
        for (int i = 0; i < 4; i++)
#pragma unroll
            for (int j = 0; j < 4; j++) o[i][j] += a[i] * bb[j];
    }
    __syncthreads();

    // Scrambled bf16 store (replicates reference reshape quirk)
#pragma unroll
    for (int i = 0; i < 4; i++) {
        int s_loc = ty * 4 + i;
        int s_b   = c * CHUNK + s_loc;
        int jj    = n * S_ + s_b;
        int s2    = jj >> 3;
        int n2    = jj & 7;
        float inv = 1.f / denom[s_loc];
        size_t obase = (size_t)(b * S_ + s2) * 512 + (size_t)n2 * 64;
#pragma unroll
        for (int v = 0; v < 4; v++)
            av[obase + tx * 4 + v] = f2bf(o[i][v] * inv);
    }
}

// ---------------------------------------------------------------------------
extern "C" void kernel_launch(void* const* d_in, const int* in_sizes, int n_in,
                              void* d_out, int out_size, void* d_ws, size_t ws_size,
                              hipStream_t stream)
{
    const float* q_in = (const float*)d_in[0];
    const float* k_in = (const float*)d_in[1];
    const float* v_in = (const float*)d_in[2];
    const float* wq   = (const float*)d_in[3];
    const float* bq   = (const float*)d_in[4];
    const float* wk   = (const float*)d_in[5];
    const float* bk   = (const float*)d_in[6];
    const float* wv   = (const float*)d_in[7];
    const float* bv   = (const float*)d_in[8];
    const float* wo   = (const float*)d_in[9];
    const float* bo   = (const float*)d_in[10];
    float* out = (float*)d_out;

    const size_t PLANE = (size_t)BS_ * ND_;   // 2097152 elems

    // f32 region
    float* ws = (float*)d_ws;
    float* pq = ws;                  // PLANE f32
    float* pk = pq + PLANE;
    float* pv = pk + PLANE;
    float* Mb = pv + PLANE;          // PLANE f32
    float* zb = Mb + PLANE;          // 32768 f32
    // bf16 region (after f32 region)
    unsigned short* u16 = (unsigned short*)(zb + 32768);
    unsigned short* qb  = u16;                   // PLANE
    unsigned short* kb  = qb + PLANE;
    unsigned short* vb  = kb + PLANE;
    unsigned short* avb = vb + PLANE;            // PLANE
    unsigned short* wqt = avb + PLANE;           // 262144 each
    unsigned short* wkt = wqt + 262144;
    unsigned short* wvt = wkt + 262144;
    unsigned short* wot = wvt + 262144;

    // K0a: activations f32->bf16
    convert_act_kernel<<<dim3(1024, 3), 256, 0, stream>>>(q_in, k_in, v_in, qb, kb, vb);
    // K0b: weights transpose+convert
    convert_wt_kernel<<<dim3(8, 8, 4), 256, 0, stream>>>(wq, wk, wv, wo, wqt, wkt, wvt, wot);
    // K1: QKV projections (MFMA bf16) + feature map
    qkv_proj_kernel<<<dim3(4, 32, 3), 256, 0, stream>>>(
        qb, kb, vb, wqt, wkt, wvt, bq, bk, bv, pq, pk, pv);
    // K2: per-chunk K^T V partials
    chunk_kv_kernel<<<dim3(NCH, NBN), 256, 0, stream>>>(pk, pv, Mb, zb);
    // K3: exclusive scan over chunks
    scan_kernel<<<dim3(17, NBN), 256, 0, stream>>>(Mb, zb);
    // K4: per-chunk causal attention -> bf16 av (scrambled layout)
    chunk_attn_kernel<<<dim3(NCH, NBN), 256, 0, stream>>>(pq, pk, pv, Mb, zb, avb);
    // K5: output projection (MFMA bf16)
    out_proj_kernel<<<dim3(4, 32), 256, 0, stream>>>(avb, wot, bo, out);
}

// Round 5
// 157.784 us; speedup vs baseline: 1.7789x; 1.1713x over previous
//
#include <hip/hip_runtime.h>
#include <hip/hip_bf16.h>
#include <cstdint>

// Problem constants
#define B_    2
#define S_    2048
#define H_    512
#define N_    8
#define D_    64
#define BS_   4096      // B*S
#define CHUNK 64
#define NCH   32        // S_/CHUNK
#define NBN   16        // B*N
#define EPS_  1e-6f

typedef __attribute__((ext_vector_type(4))) float  f32x4;
typedef __attribute__((ext_vector_type(8))) short  short8;
typedef __attribute__((ext_vector_type(4))) short  short4_t;

static __device__ __forceinline__ unsigned short f2bf(float x) {
    __hip_bfloat16 h = __float2bfloat16(x);
    return *reinterpret_cast<unsigned short*>(&h);
}
static __device__ __forceinline__ float bf2f(unsigned short u) {
    unsigned int v = ((unsigned int)u) << 16;
    float f;
    __builtin_memcpy(&f, &v, 4);
    return f;
}

// ---------------------------------------------------------------------------
// K0a: input activations f32 -> bf16.  grid (1024, 3), block 256
// ---------------------------------------------------------------------------
__global__ __launch_bounds__(256) void convert_act_kernel(
    const float* __restrict__ q, const float* __restrict__ k, const float* __restrict__ v,
    unsigned short* __restrict__ qb, unsigned short* __restrict__ kb, unsigned short* __restrict__ vb)
{
    const int p = blockIdx.y;
    const float* src = (p == 0) ? q : (p == 1) ? k : v;
    unsigned short* dst = (p == 0) ? qb : (p == 1) ? kb : vb;
    size_t idx = ((size_t)blockIdx.x * 256 + threadIdx.x) * 8;
    float4 a = *reinterpret_cast<const float4*>(src + idx);
    float4 b = *reinterpret_cast<const float4*>(src + idx + 4);
    short8 o;
    o[0] = (short)f2bf(a.x); o[1] = (short)f2bf(a.y);
    o[2] = (short)f2bf(a.z); o[3] = (short)f2bf(a.w);
    o[4] = (short)f2bf(b.x); o[5] = (short)f2bf(b.y);
    o[6] = (short)f2bf(b.z); o[7] = (short)f2bf(b.w);
    *reinterpret_cast<short8*>(dst + idx) = o;
}

// ---------------------------------------------------------------------------
// K0b: weight transpose+convert: Wt[c][k] = bf16(W[k][c]).  grid (8,8,4)
// ---------------------------------------------------------------------------
__global__ __launch_bounds__(256) void convert_wt_kernel(
    const float* __restrict__ wq, const float* __restrict__ wk,
    const float* __restrict__ wv, const float* __restrict__ wo,
    unsigned short* __restrict__ wqt, unsigned short* __restrict__ wkt,
    unsigned short* __restrict__ wvt, unsigned short* __restrict__ wot)
{
    const int m = blockIdx.z;
    const float* W = (m == 0) ? wq : (m == 1) ? wk : (m == 2) ? wv : wo;
    unsigned short* Wt = (m == 0) ? wqt : (m == 1) ? wkt : (m == 2) ? wvt : wot;

    __shared__ float t[64][65];
    const int k0 = blockIdx.y * 64, c0 = blockIdx.x * 64;
    const int tid = threadIdx.x;
    const int rr = tid >> 6;
    const int cc = tid & 63;
#pragma unroll
    for (int p = 0; p < 16; p++) {
        int kl = rr + p * 4;
        t[kl][cc] = W[(size_t)(k0 + kl) * 512 + c0 + cc];
    }
    __syncthreads();
#pragma unroll
    for (int p = 0; p < 16; p++) {
        int cl = rr + p * 4;
        Wt[(size_t)(c0 + cl) * 512 + k0 + cc] = f2bf(t[cc][cl]);
    }
}

// ---------------------------------------------------------------------------
// MFMA GEMM body: [4096,512](bf16) x Wt[512,512](bf16 B^T) -> [4096,512]
// MODE 0: phi, bf16 row-major out        (Q)
// MODE 1: phi, bf16 row-major + [col][t] transposed out   (K)
// MODE 2: no phi, transposed out only    (V)
// MODE 3: no phi, f32 row-major out      (out-proj)
// ---------------------------------------------------------------------------
template<int MODE>
__device__ __forceinline__ void mfma_gemm_body(
    const unsigned short* __restrict__ X, const unsigned short* __restrict__ Wt,
    const float* __restrict__ bias,
    unsigned short* __restrict__ Obf, unsigned short* __restrict__ Ot,
    float* __restrict__ Of)
{
    __shared__ unsigned short As[128][72];
    __shared__ unsigned short Bs[128][72];

    const int tid  = threadIdx.x;
    const int lane = tid & 63;
    const int w    = tid >> 6;
    const int wm   = (w & 1) * 64;
    const int wn   = (w >> 1) * 64;
    const int row0 = blockIdx.y * 128;
    const int col0 = blockIdx.x * 128;
    const int frow = lane & 15;
    const int fk   = (lane >> 4) * 8;

    f32x4 acc[4][4];
#pragma unroll
    for (int m = 0; m < 4; m++)
#pragma unroll
        for (int n = 0; n < 4; n++) acc[m][n] = (f32x4){0.f, 0.f, 0.f, 0.f};

    const int lr = tid >> 3;
    const int lc = (tid & 7) * 8;

    for (int k0 = 0; k0 < 512; k0 += 64) {
#pragma unroll
        for (int p = 0; p < 4; p++) {
            int r = lr + p * 32;
            *reinterpret_cast<short8*>(&As[r][lc]) =
                *reinterpret_cast<const short8*>(X + (size_t)(row0 + r) * 512 + k0 + lc);
            *reinterpret_cast<short8*>(&Bs[r][lc]) =
                *reinterpret_cast<const short8*>(Wt + (size_t)(col0 + r) * 512 + k0 + lc);
        }
        __syncthreads();
#pragma unroll
        for (int kk = 0; kk < 64; kk += 32) {
            short8 a[4], b[4];
#pragma unroll
            for (int m = 0; m < 4; m++)
                a[m] = *reinterpret_cast<const short8*>(&As[wm + m * 16 + frow][kk + fk]);
#pragma unroll
            for (int n = 0; n < 4; n++)
                b[n] = *reinterpret_cast<const short8*>(&Bs[wn + n * 16 + frow][kk + fk]);
#pragma unroll
            for (int m = 0; m < 4; m++)
#pragma unroll
                for (int n = 0; n < 4; n++)
                    acc[m][n] = __builtin_amdgcn_mfma_f32_16x16x32_bf16(
                        a[m], b[n], acc[m][n], 0, 0, 0);
        }
        __syncthreads();
    }

    // Epilogue. C/D layout: col=lane&15, row=(lane>>4)*4+r (m89-verified)
#pragma unroll
    for (int n = 0; n < 4; n++) {
        int col = col0 + wn + n * 16 + frow;
        float bv_ = bias[col];
#pragma unroll
        for (int m = 0; m < 4; m++) {
            int rbase = row0 + wm + m * 16 + (lane >> 4) * 4;
            short4_t t4;
#pragma unroll
            for (int r = 0; r < 4; r++) {
                float val = acc[m][n][r] + bv_;
                if (MODE == 0 || MODE == 1)
                    val = (val > 0.f) ? (val + 1.f) : __expf(val);   // elu+1
                if (MODE == 3) {
                    Of[(size_t)(rbase + r) * 512 + col] = val;
                } else {
                    unsigned short ub = f2bf(val);
                    t4[r] = (short)ub;
                    if (MODE == 0 || MODE == 1)
                        Obf[(size_t)(rbase + r) * 512 + col] = ub;
                }
            }
            if (MODE == 1 || MODE == 2) {
                int bb = rbase >> 11;          // batch
                int t_ = rbase & 2047;         // time within batch
                *reinterpret_cast<short4_t*>(
                    Ot + (size_t)bb * (512 * 2048) + (size_t)col * 2048 + t_) = t4;
            }
        }
    }
}

// K1: QKV projections. grid (4, 32, 3), block 256
__global__ __launch_bounds__(256) void qkv_proj_kernel(
    const unsigned short* __restrict__ qb, const unsigned short* __restrict__ kb,
    const unsigned short* __restrict__ vb,
    const unsigned short* __restrict__ wqt, const unsigned short* __restrict__ wkt,
    const unsigned short* __restrict__ wvt,
    const float* __restrict__ bq, const float* __restrict__ bk, const float* __restrict__ bv,
    unsigned short* __restrict__ pq, unsigned short* __restrict__ pk,
    unsigned short* __restrict__ pkT, unsigned short* __restrict__ pvT)
{
    int m = blockIdx.z;
    if (m == 0)      mfma_gemm_body<0>(qb, wqt, bq, pq, nullptr, nullptr);
    else if (m == 1) mfma_gemm_body<1>(kb, wkt, bk, pk, pkT, nullptr);
    else             mfma_gemm_body<2>(vb, wvt, bv, nullptr, pvT, nullptr);
}

// K5: output projection. grid (4, 32), block 256
__global__ __launch_bounds__(256) void out_proj_kernel(
    const unsigned short* __restrict__ avb, const unsigned short* __restrict__ wot,
    const float* __restrict__ bo, float* __restrict__ out)
{
    mfma_gemm_body<3>(avb, wot, bo, nullptr, nullptr, out);
}

// ---------------------------------------------------------------------------
// K2 (MFMA): per-chunk transposed state  M'_c[d][h] = sum_t V[t][d]*K[t][h]
// and z_c[h] = sum_t K[t][h].  grid (NCH, NBN), block 256 (4 waves).
// ---------------------------------------------------------------------------
__global__ __launch_bounds__(256) void chunk_kv_kernel(
    const unsigned short* __restrict__ pkT, const unsigned short* __restrict__ pvT,
    float* __restrict__ Mb, float* __restrict__ zb)
{
    __shared__ unsigned short KT[64][72];
    __shared__ unsigned short VT[64][72];
    const int c = blockIdx.x, bn = blockIdx.y;
    const int b = bn >> 3, n = bn & 7;
    const int t0 = c * 64;
    const int col0 = n * 64;
    const size_t base_b = (size_t)b * 512 * 2048;
    const int tid = threadIdx.x;
    const int lane = tid & 63, w = tid >> 6;

#pragma unroll
    for (int p = 0; p < 2; p++) {
        int r  = (tid >> 3) + p * 32;
        int c8 = (tid & 7) * 8;
        size_t g = base_b + (size_t)(col0 + r) * 2048 + t0 + c8;
        *reinterpret_cast<short8*>(&KT[r][c8]) = *reinterpret_cast<const short8*>(pkT + g);
        *reinterpret_cast<short8*>(&VT[r][c8]) = *reinterpret_cast<const short8*>(pvT + g);
    }
    __syncthreads();

    const int frow = lane & 15, grp = lane >> 4, fk = grp * 8;
    f32x4 acc[4];
#pragma unroll
    for (int nf = 0; nf < 4; nf++) acc[nf] = (f32x4){0.f, 0.f, 0.f, 0.f};

#pragma unroll
    for (int ks = 0; ks < 2; ks++) {
        short8 a = *reinterpret_cast<const short8*>(&VT[w * 16 + frow][ks * 32 + fk]);
#pragma unroll
        for (int nf = 0; nf < 4; nf++) {
            short8 bfr = *reinterpret_cast<const short8*>(&KT[nf * 16 + frow][ks * 32 + fk]);
            acc[nf] = __builtin_amdgcn_mfma_f32_16x16x32_bf16(a, bfr, acc[nf], 0, 0, 0);
        }
    }

    size_t mbase = ((size_t)bn * NCH + c) * 4096;
#pragma unroll
    for (int nf = 0; nf < 4; nf++)
#pragma unroll
        for (int r = 0; r < 4; r++) {
            int d = w * 16 + grp * 4 + r;
            Mb[mbase + (size_t)d * 64 + nf * 16 + frow] = acc[nf][r];
        }

    if (tid < 64) {
        float s = 0.f;
        for (int t = 0; t < 64; t++) s += bf2f(KT[tid][t]);
        zb[((size_t)bn * NCH + c) * 64 + tid] = s;
    }
}

// ---------------------------------------------------------------------------
// K3: exclusive prefix scan over chunks (in place).  grid (17, 16)
// ---------------------------------------------------------------------------
__global__ __launch_bounds__(256) void scan_kernel(float* __restrict__ Mb,
                                                   float* __restrict__ zb)
{
    const int bn  = blockIdx.y;
    const int tid = threadIdx.x;
    if (blockIdx.x < 16) {
        const int e = blockIdx.x * 256 + tid;
        float run = 0.f;
        for (int c = 0; c < NCH; c++) {
            size_t idx = ((size_t)bn * NCH + c) * 4096 + e;
            float t = Mb[idx];
            Mb[idx] = run;
            run += t;
        }
    } else if (tid < 64) {
        float run = 0.f;
        for (int c = 0; c < NCH; c++) {
            size_t idx = ((size_t)bn * NCH + c) * 64 + tid;
            float t = zb[idx];
            zb[idx] = run;
            run += t;
        }
    }
}

// ---------------------------------------------------------------------------
// K4 (MFMA): per-chunk attention.
//   A = tril(Q K^T); O = A V + Q Sp'; denom = qz_prev + rowsum(A) + eps
//   av = O/denom stored bf16 in reference's scrambled reshape layout.
// grid (NCH, NBN), block 256 (4 waves; wave w owns rows w*16..w*16+15)
// ---------------------------------------------------------------------------
__global__ __launch_bounds__(256) void chunk_attn_kernel(
    const unsigned short* __restrict__ pq, const unsigned short* __restrict__ pk,
    const unsigned short* __restrict__ pvT, const float* __restrict__ Mb,
    const float* __restrict__ zb, unsigned short* __restrict__ av)
{
    __shared__ unsigned short Qs[64][72], Ks[64][72], VT[64][72], SpT[64][72], Ab[64][72];
    __shared__ float zs[64], dQZ[64], dAS[64];

    const int c = blockIdx.x, bn = blockIdx.y;
    const int b = bn >> 3, n = bn & 7;
    const int row0 = b * S_ + c * 64;
    const int col0 = n * 64;
    const int t0 = c * 64;
    const size_t vbase = (size_t)b * 512 * 2048;
    const size_t mbase = ((size_t)bn * NCH + c) * 4096;
    const int tid = threadIdx.x, lane = tid & 63, w = tid >> 6;

    // stage
#pragma unroll
    for (int p = 0; p < 2; p++) {
        int r  = (tid >> 3) + p * 32;
        int c8 = (tid & 7) * 8;
        *reinterpret_cast<short8*>(&Qs[r][c8]) =
            *reinterpret_cast<const short8*>(pq + (size_t)(row0 + r) * 512 + col0 + c8);
        *reinterpret_cast<short8*>(&Ks[r][c8]) =
            *reinterpret_cast<const short8*>(pk + (size_t)(row0 + r) * 512 + col0 + c8);
        *reinterpret_cast<short8*>(&VT[r][c8]) =
            *reinterpret_cast<const short8*>(pvT + vbase + (size_t)(col0 + r) * 2048 + t0 + c8);
    }
#pragma unroll
    for (int p = 0; p < 16; p++) {
        int i = p * 256 + tid;
        SpT[i >> 6][i & 63] = f2bf(Mb[mbase + i]);
    }
    if (tid < 64) zs[tid] = zb[((size_t)bn * NCH + c) * 64 + tid];
    __syncthreads();

    const int frow = lane & 15, grp = lane >> 4, fk = grp * 8;
    const int srow = w * 16;

    // QK^T
    f32x4 a1[4];
#pragma unroll
    for (int tf = 0; tf < 4; tf++) a1[tf] = (f32x4){0.f, 0.f, 0.f, 0.f};
#pragma unroll
    for (int ks = 0; ks < 2; ks++) {
        short8 qa = *reinterpret_cast<const short8*>(&Qs[srow + frow][ks * 32 + fk]);
#pragma unroll
        for (int tf = 0; tf < 4; tf++) {
            short8 kb = *reinterpret_cast<const short8*>(&Ks[tf * 16 + frow][ks * 32 + fk]);
            a1[tf] = __builtin_amdgcn_mfma_f32_16x16x32_bf16(qa, kb, a1[tf], 0, 0, 0);
        }
    }

    // mask + rowsum + Ab
    float rs[4] = {0.f, 0.f, 0.f, 0.f};
#pragma unroll
    for (int tf = 0; tf < 4; tf++) {
        int t_ = tf * 16 + frow;
#pragma unroll
        for (int r = 0; r < 4; r++) {
            int s_ = srow + grp * 4 + r;
            float v = (t_ <= s_) ? a1[tf][r] : 0.f;
            rs[r] += v;
            Ab[s_][t_] = f2bf(v);
        }
    }
#pragma unroll
    for (int msk = 1; msk < 16; msk <<= 1)
#pragma unroll
        for (int r = 0; r < 4; r++) rs[r] += __shfl_xor(rs[r], msk);
    if (frow == 0) {
#pragma unroll
        for (int r = 0; r < 4; r++) dAS[srow + grp * 4 + r] = rs[r];
    }

    // q·z_prev (wave 0)
    if (tid < 64) {
        float s = 0.f;
        for (int h = 0; h < 64; h++) s += bf2f(Qs[tid][h]) * zs[h];
        dQZ[tid] = s;
    }
    __syncthreads();

    // O = A V + Q Sp'
    f32x4 o[4];
#pragma unroll
    for (int df = 0; df < 4; df++) o[df] = (f32x4){0.f, 0.f, 0.f, 0.f};
#pragma unroll
    for (int ks = 0; ks < 2; ks++) {
        short8 aa = *reinterpret_cast<const short8*>(&Ab[srow + frow][ks * 32 + fk]);
        short8 qa = *reinterpret_cast<const short8*>(&Qs[srow + frow][ks * 32 + fk]);
#pragma unroll
        for (int df = 0; df < 4; df++) {
            short8 vb = *reinterpret_cast<const short8*>(&VT[df * 16 + frow][ks * 32 + fk]);
            short8 sp = *reinterpret_cast<const short8*>(&SpT[df * 16 + frow][ks * 32 + fk]);
            o[df] = __builtin_amdgcn_mfma_f32_16x16x32_bf16(aa, vb, o[df], 0, 0, 0);
            o[df] = __builtin_amdgcn_mfma_f32_16x16x32_bf16(qa, sp, o[df], 0, 0, 0);
        }
    }

    // divide + scrambled bf16 store
    float inv[4];
    size_t obase[4];
#pragma unroll
    for (int r = 0; r < 4; r++) {
        int s_loc = srow + grp * 4 + r;
        inv[r] = 1.f / (dQZ[s_loc] + dAS[s_loc] + EPS_);
        int s_b = c * 64 + s_loc;
        int jj  = n * S_ + s_b;
        obase[r] = (size_t)(b * S_ + (jj >> 3)) * 512 + (size_t)(jj & 7) * 64;
    }
#pragma unroll
    for (int df = 0; df < 4; df++) {
        int d = df * 16 + frow;
#pragma unroll
        for (int r = 0; r < 4; r++)
            av[obase[r] + d] = f2bf(o[df][r] * inv[r]);
    }
}

// ---------------------------------------------------------------------------
extern "C" void kernel_launch(void* const* d_in, const int* in_sizes, int n_in,
                              void* d_out, int out_size, void* d_ws, size_t ws_size,
                              hipStream_t stream)
{
    const float* q_in = (const float*)d_in[0];
    const float* k_in = (const float*)d_in[1];
    const float* v_in = (const float*)d_in[2];
    const float* wq   = (const float*)d_in[3];
    const float* bq   = (const float*)d_in[4];
    const float* wk   = (const float*)d_in[5];
    const float* bk   = (const float*)d_in[6];
    const float* wv   = (const float*)d_in[7];
    const float* bv   = (const float*)d_in[8];
    const float* wo   = (const float*)d_in[9];
    const float* bo   = (const float*)d_in[10];
    float* out = (float*)d_out;

    const size_t PLANE = (size_t)BS_ * 512;   // 2,097,152 elems

    float* ws = (float*)d_ws;
    float* Mb   = ws;                         // PLANE f32
    float* zbuf = Mb + PLANE;                 // 32768 f32
    unsigned short* u16 = (unsigned short*)(zbuf + 32768);
    unsigned short* qb  = u16;                // PLANE each
    unsigned short* kb  = qb  + PLANE;
    unsigned short* vb  = kb  + PLANE;
    unsigned short* pq  = vb  + PLANE;
    unsigned short* pk  = pq  + PLANE;
    unsigned short* pkT = pk  + PLANE;
    unsigned short* pvT = pkT + PLANE;
    unsigned short* avb = pvT + PLANE;
    unsigned short* wqt = avb + PLANE;        // 262144 each
    unsigned short* wkt = wqt + 262144;
    unsigned short* wvt = wkt + 262144;
    unsigned short* wot = wvt + 262144;

    convert_act_kernel<<<dim3(1024, 3), 256, 0, stream>>>(q_in, k_in, v_in, qb, kb, vb);
    convert_wt_kernel<<<dim3(8, 8, 4), 256, 0, stream>>>(wq, wk, wv, wo, wqt, wkt, wvt, wot);
    qkv_proj_kernel<<<dim3(4, 32, 3), 256, 0, stream>>>(
        qb, kb, vb, wqt, wkt, wvt, bq, bk, bv, pq, pk, pkT, pvT);
    chunk_kv_kernel<<<dim3(NCH, NBN), 256, 0, stream>>>(pkT, pvT, Mb, zbuf);
    scan_kernel<<<dim3(17, NBN), 256, 0, stream>>>(Mb, zbuf);
    chunk_attn_kernel<<<dim3(NCH, NBN), 256, 0, stream>>>(pq, pk, pvT, Mb, zbuf, avb);
    out_proj_kernel<<<dim3(4, 32), 256, 0, stream>>>(avb, wot, bo, out);
}

// Round 6
// 155.391 us; speedup vs baseline: 1.8063x; 1.0154x over previous
//
#include <hip/hip_runtime.h>
#include <hip/hip_bf16.h>
#include <cstdint>

// Problem constants
#define B_    2
#define S_    2048
#define H_    512
#define N_    8
#define D_    64
#define BS_   4096      // B*S
#define CHUNK 64
#define NCH   32        // S_/CHUNK
#define NBN   16        // B*N
#define EPS_  1e-6f

typedef __attribute__((ext_vector_type(4))) float  f32x4;
typedef __attribute__((ext_vector_type(8))) short  short8;
typedef __attribute__((ext_vector_type(4))) short  short4_t;

static __device__ __forceinline__ unsigned short f2bf(float x) {
    __hip_bfloat16 h = __float2bfloat16(x);
    return *reinterpret_cast<unsigned short*>(&h);
}
static __device__ __forceinline__ float bf2f(unsigned short u) {
    unsigned int v = ((unsigned int)u) << 16;
    float f;
    __builtin_memcpy(&f, &v, 4);
    return f;
}

// ---------------------------------------------------------------------------
// K0b: weight transpose+convert: Wt[c][k] = bf16(W[k][c]).  grid (8,8,4)
// ---------------------------------------------------------------------------
__global__ __launch_bounds__(256) void convert_wt_kernel(
    const float* __restrict__ wq, const float* __restrict__ wk,
    const float* __restrict__ wv, const float* __restrict__ wo,
    unsigned short* __restrict__ wqt, unsigned short* __restrict__ wkt,
    unsigned short* __restrict__ wvt, unsigned short* __restrict__ wot)
{
    const int m = blockIdx.z;
    const float* W = (m == 0) ? wq : (m == 1) ? wk : (m == 2) ? wv : wo;
    unsigned short* Wt = (m == 0) ? wqt : (m == 1) ? wkt : (m == 2) ? wvt : wot;

    __shared__ float t[64][65];
    const int k0 = blockIdx.y * 64, c0 = blockIdx.x * 64;
    const int tid = threadIdx.x;
    const int rr = tid >> 6;
    const int cc = tid & 63;
#pragma unroll
    for (int p = 0; p < 16; p++) {
        int kl = rr + p * 4;
        t[kl][cc] = W[(size_t)(k0 + kl) * 512 + c0 + cc];
    }
    __syncthreads();
#pragma unroll
    for (int p = 0; p < 16; p++) {
        int cl = rr + p * 4;
        Wt[(size_t)(c0 + cl) * 512 + k0 + cc] = f2bf(t[cc][cl]);
    }
}

// ---------------------------------------------------------------------------
// MFMA GEMM body, 128x64 tile, BK=64, 256 thr (4 waves as 2x2 -> 64x32 each).
// X is f32 (MODE 0..2, converted during staging) or bf16 (MODE 3).
// MODE 0: phi, bf16 row-major out        (Q)
// MODE 1: phi, bf16 row-major + [col][t] transposed out   (K)
// MODE 2: no phi, transposed out only    (V)
// MODE 3: no phi, f32 row-major out      (out-proj, bf16 X)
// ---------------------------------------------------------------------------
template<int MODE>
__device__ __forceinline__ void mfma_gemm_body(
    const void* __restrict__ Xv, const unsigned short* __restrict__ Wt,
    const float* __restrict__ bias,
    unsigned short* __restrict__ Obf, unsigned short* __restrict__ Ot,
    float* __restrict__ Of)
{
    __shared__ unsigned short As[128][72];
    __shared__ unsigned short Bs[64][72];

    const int tid  = threadIdx.x;
    const int lane = tid & 63;
    const int w    = tid >> 6;
    const int wm   = (w & 1) * 64;
    const int wn   = (w >> 1) * 32;
    const int row0 = blockIdx.y * 128;
    const int col0 = blockIdx.x * 64;
    const int frow = lane & 15;
    const int fk   = (lane >> 4) * 8;

    f32x4 acc[4][2];
#pragma unroll
    for (int m = 0; m < 4; m++)
#pragma unroll
        for (int n = 0; n < 2; n++) acc[m][n] = (f32x4){0.f, 0.f, 0.f, 0.f};

    const int lr = tid >> 3;          // 0..31
    const int lc = (tid & 7) * 8;     // 0..56

    for (int k0 = 0; k0 < 512; k0 += 64) {
        // A tile 128x64
#pragma unroll
        for (int p = 0; p < 4; p++) {
            int r = lr + p * 32;
            if (MODE == 3) {
                const unsigned short* X = (const unsigned short*)Xv;
                *reinterpret_cast<short8*>(&As[r][lc]) =
                    *reinterpret_cast<const short8*>(X + (size_t)(row0 + r) * 512 + k0 + lc);
            } else {
                const float* X = (const float*)Xv;
                const float* src = X + (size_t)(row0 + r) * 512 + k0 + lc;
                float4 x0 = *reinterpret_cast<const float4*>(src);
                float4 x1 = *reinterpret_cast<const float4*>(src + 4);
                short8 o;
                o[0] = (short)f2bf(x0.x); o[1] = (short)f2bf(x0.y);
                o[2] = (short)f2bf(x0.z); o[3] = (short)f2bf(x0.w);
                o[4] = (short)f2bf(x1.x); o[5] = (short)f2bf(x1.y);
                o[6] = (short)f2bf(x1.z); o[7] = (short)f2bf(x1.w);
                *reinterpret_cast<short8*>(&As[r][lc]) = o;
            }
        }
        // B tile 64x64
#pragma unroll
        for (int p = 0; p < 2; p++) {
            int r = (tid >> 3) + p * 32;
            *reinterpret_cast<short8*>(&Bs[r][lc]) =
                *reinterpret_cast<const short8*>(Wt + (size_t)(col0 + r) * 512 + k0 + lc);
        }
        __syncthreads();
#pragma unroll
        for (int kk = 0; kk < 64; kk += 32) {
            short8 a[4], b[2];
#pragma unroll
            for (int m = 0; m < 4; m++)
                a[m] = *reinterpret_cast<const short8*>(&As[wm + m * 16 + frow][kk + fk]);
#pragma unroll
            for (int n = 0; n < 2; n++)
                b[n] = *reinterpret_cast<const short8*>(&Bs[wn + n * 16 + frow][kk + fk]);
#pragma unroll
            for (int m = 0; m < 4; m++)
#pragma unroll
                for (int n = 0; n < 2; n++)
                    acc[m][n] = __builtin_amdgcn_mfma_f32_16x16x32_bf16(
                        a[m], b[n], acc[m][n], 0, 0, 0);
        }
        __syncthreads();
    }

    // Epilogue. C/D: col=lane&15, row=(lane>>4)*4+r (m89-verified)
#pragma unroll
    for (int n = 0; n < 2; n++) {
        int col = col0 + wn + n * 16 + frow;
        float bv_ = bias[col];
#pragma unroll
        for (int m = 0; m < 4; m++) {
            int rbase = row0 + wm + m * 16 + (lane >> 4) * 4;
            short4_t t4;
#pragma unroll
            for (int r = 0; r < 4; r++) {
                float val = acc[m][n][r] + bv_;
                if (MODE == 0 || MODE == 1)
                    val = (val > 0.f) ? (val + 1.f) : __expf(val);   // elu+1
                if (MODE == 3) {
                    Of[(size_t)(rbase + r) * 512 + col] = val;
                } else {
                    unsigned short ub = f2bf(val);
                    t4[r] = (short)ub;
                    if (MODE == 0 || MODE == 1)
                        Obf[(size_t)(rbase + r) * 512 + col] = ub;
                }
            }
            if (MODE == 1 || MODE == 2) {
                int bb = rbase >> 11;          // batch
                int t_ = rbase & 2047;         // time within batch
                *reinterpret_cast<short4_t*>(
                    Ot + (size_t)bb * (512 * 2048) + (size_t)col * 2048 + t_) = t4;
            }
        }
    }
}

// K1: QKV projections from f32 inputs. grid (8, 32, 3), block 256
__global__ __launch_bounds__(256) void qkv_proj_kernel(
    const float* __restrict__ q_in, const float* __restrict__ k_in,
    const float* __restrict__ v_in,
    const unsigned short* __restrict__ wqt, const unsigned short* __restrict__ wkt,
    const unsigned short* __restrict__ wvt,
    const float* __restrict__ bq, const float* __restrict__ bk, const float* __restrict__ bv,
    unsigned short* __restrict__ pq, unsigned short* __restrict__ pk,
    unsigned short* __restrict__ pkT, unsigned short* __restrict__ pvT)
{
    int m = blockIdx.z;
    if (m == 0)      mfma_gemm_body<0>(q_in, wqt, bq, pq, nullptr, nullptr);
    else if (m == 1) mfma_gemm_body<1>(k_in, wkt, bk, pk, pkT, nullptr);
    else             mfma_gemm_body<2>(v_in, wvt, bv, nullptr, pvT, nullptr);
}

// K5: output projection. grid (8, 32), block 256
__global__ __launch_bounds__(256) void out_proj_kernel(
    const unsigned short* __restrict__ avb, const unsigned short* __restrict__ wot,
    const float* __restrict__ bo, float* __restrict__ out)
{
    mfma_gemm_body<3>(avb, wot, bo, nullptr, nullptr, out);
}

// ---------------------------------------------------------------------------
// K23 (fused chunk-KV + exclusive scan):
//   M'_c[d][h] = sum_{t in chunk c} V[t,d]*K[t,h];  Mb[bn][c] = exclusive prefix
//   z_c[h] = sum_t K[t,h];                          zb[bn][c] = exclusive prefix
// grid (16, 16): x = (dblk<<2)|hblk tile of 16x16, y = bn. block 256 (4 waves).
// Wave w scans chunks w*8..w*8+7 with register-held local prefixes, then a
// block-level scan over wave totals supplies the carry.
// MFMA fragments loaded DIRECTLY from global (pvT/pkT rows are d/h, k = t).
// ---------------------------------------------------------------------------
__global__ __launch_bounds__(256) void chunk_kvscan_kernel(
    const unsigned short* __restrict__ pkT, const unsigned short* __restrict__ pvT,
    float* __restrict__ Mb, float* __restrict__ zb)
{
    __shared__ float waveTot[4][256];     // per-wave state totals
    __shared__ float zTot[4][16];         // per-wave z totals

    const int tile = blockIdx.x;
    const int bn   = blockIdx.y;
    const int d0   = (tile >> 2) * 16;
    const int h0   = (tile & 3) * 16;
    const int b = bn >> 3, n = bn & 7;
    const int tid = threadIdx.x, lane = tid & 63, w = tid >> 6;
    const int frow = lane & 15, grp = lane >> 4, fk = grp * 8;
    const bool do_z = (tile >> 2) == 0;

    const size_t vrow = (size_t)b * (512 * 2048) + (size_t)(n * 64 + d0 + frow) * 2048;
    const size_t krow = (size_t)b * (512 * 2048) + (size_t)(n * 64 + h0 + frow) * 2048;

    f32x4 run = (f32x4){0.f, 0.f, 0.f, 0.f};
    f32x4 loc[8];
    float runz = 0.f, locz[8];

#pragma unroll
    for (int c = 0; c < 8; c++) {
        int t0 = (w * 8 + c) * 64;
        loc[c] = run;
        locz[c] = runz;
        short8 a0 = *reinterpret_cast<const short8*>(pvT + vrow + t0 + fk);
        short8 a1 = *reinterpret_cast<const short8*>(pvT + vrow + t0 + 32 + fk);
        short8 b0 = *reinterpret_cast<const short8*>(pkT + krow + t0 + fk);
        short8 b1 = *reinterpret_cast<const short8*>(pkT + krow + t0 + 32 + fk);
        run = __builtin_amdgcn_mfma_f32_16x16x32_bf16(a0, b0, run, 0, 0, 0);
        run = __builtin_amdgcn_mfma_f32_16x16x32_bf16(a1, b1, run, 0, 0, 0);
        if (do_z) {
            float zp = 0.f;
#pragma unroll
            for (int j = 0; j < 8; j++) zp += bf2f((unsigned short)b0[j]) + bf2f((unsigned short)b1[j]);
            zp += __shfl_xor(zp, 16);
            zp += __shfl_xor(zp, 32);
            runz += zp;
        }
    }

    // publish wave totals
#pragma unroll
    for (int r = 0; r < 4; r++)
        waveTot[w][(grp * 4 + r) * 16 + frow] = run[r];
    if (do_z && lane < 16) zTot[w][frow] = runz;
    __syncthreads();

    // carry = sum of totals of preceding waves
    f32x4 carry = (f32x4){0.f, 0.f, 0.f, 0.f};
    float carryz = 0.f;
    for (int pw = 0; pw < w; pw++) {
#pragma unroll
        for (int r = 0; r < 4; r++)
            carry[r] += waveTot[pw][(grp * 4 + r) * 16 + frow];
        carryz += zTot[pw][frow];
    }

    // store exclusive prefixes
#pragma unroll
    for (int c = 0; c < 8; c++) {
        size_t mbase = ((size_t)bn * NCH + (w * 8 + c)) * 4096;
#pragma unroll
        for (int r = 0; r < 4; r++)
            Mb[mbase + (size_t)(d0 + grp * 4 + r) * 64 + h0 + frow] = carry[r] + loc[c][r];
        if (do_z && lane < 16)
            zb[((size_t)bn * NCH + (w * 8 + c)) * 64 + h0 + frow] = carryz + locz[c];
    }
}

// ---------------------------------------------------------------------------
// K4 (MFMA): per-chunk attention.
//   A = tril(Q K^T); O = A V + Q Sp'; denom = qz_prev + rowsum(A) + eps
//   av = O/denom stored bf16 in reference's scrambled reshape layout.
// grid (NCH, NBN), block 256 (4 waves; wave w owns rows w*16..w*16+15)
// ---------------------------------------------------------------------------
__global__ __launch_bounds__(256) void chunk_attn_kernel(
    const unsigned short* __restrict__ pq, const unsigned short* __restrict__ pk,
    const unsigned short* __restrict__ pvT, const float* __restrict__ Mb,
    const float* __restrict__ zb, unsigned short* __restrict__ av)
{
    __shared__ unsigned short Qs[64][72], Ks[64][72], VT[64][72], SpT[64][72], Ab[64][72];
    __shared__ float zs[64], dqz4[64][4], dAS[64];

    const int c = blockIdx.x, bn = blockIdx.y;
    const int b = bn >> 3, n = bn & 7;
    const int row0 = b * S_ + c * 64;
    const int col0 = n * 64;
    const int t0 = c * 64;
    const size_t vbase = (size_t)b * 512 * 2048;
    const size_t mbase = ((size_t)bn * NCH + c) * 4096;
    const int tid = threadIdx.x, lane = tid & 63, w = tid >> 6;

    // stage
#pragma unroll
    for (int p = 0; p < 2; p++) {
        int r  = (tid >> 3) + p * 32;
        int c8 = (tid & 7) * 8;
        *reinterpret_cast<short8*>(&Qs[r][c8]) =
            *reinterpret_cast<const short8*>(pq + (size_t)(row0 + r) * 512 + col0 + c8);
        *reinterpret_cast<short8*>(&Ks[r][c8]) =
            *reinterpret_cast<const short8*>(pk + (size_t)(row0 + r) * 512 + col0 + c8);
        *reinterpret_cast<short8*>(&VT[r][c8]) =
            *reinterpret_cast<const short8*>(pvT + vbase + (size_t)(col0 + r) * 2048 + t0 + c8);
    }
#pragma unroll
    for (int p = 0; p < 16; p++) {
        int i = p * 256 + tid;
        SpT[i >> 6][i & 63] = f2bf(Mb[mbase + i]);
    }
    if (tid < 64) zs[tid] = zb[((size_t)bn * NCH + c) * 64 + tid];
    __syncthreads();

    const int frow = lane & 15, grp = lane >> 4, fk = grp * 8;
    const int srow = w * 16;

    // QK^T
    f32x4 a1[4];
#pragma unroll
    for (int tf = 0; tf < 4; tf++) a1[tf] = (f32x4){0.f, 0.f, 0.f, 0.f};
#pragma unroll
    for (int ks = 0; ks < 2; ks++) {
        short8 qa = *reinterpret_cast<const short8*>(&Qs[srow + frow][ks * 32 + fk]);
#pragma unroll
        for (int tf = 0; tf < 4; tf++) {
            short8 kb = *reinterpret_cast<const short8*>(&Ks[tf * 16 + frow][ks * 32 + fk]);
            a1[tf] = __builtin_amdgcn_mfma_f32_16x16x32_bf16(qa, kb, a1[tf], 0, 0, 0);
        }
    }

    // mask + rowsum + Ab
    float rs[4] = {0.f, 0.f, 0.f, 0.f};
#pragma unroll
    for (int tf = 0; tf < 4; tf++) {
        int t_ = tf * 16 + frow;
#pragma unroll
        for (int r = 0; r < 4; r++) {
            int s_ = srow + grp * 4 + r;
            float v = (t_ <= s_) ? a1[tf][r] : 0.f;
            rs[r] += v;
            Ab[s_][t_] = f2bf(v);
        }
    }
#pragma unroll
    for (int msk = 1; msk < 16; msk <<= 1)
#pragma unroll
        for (int r = 0; r < 4; r++) rs[r] += __shfl_xor(rs[r], msk);
    if (frow == 0) {
#pragma unroll
        for (int r = 0; r < 4; r++) dAS[srow + grp * 4 + r] = rs[r];
    }

    // q·z_prev, split across all 256 threads (16 MACs each)
    {
        int s = tid & 63, part = tid >> 6;
        float sdq = 0.f;
#pragma unroll
        for (int j = 0; j < 16; j++) {
            int h = part * 16 + j;
            sdq += bf2f(Qs[s][h]) * zs[h];
        }
        dqz4[s][part] = sdq;
    }
    __syncthreads();

    // O = A V + Q Sp'
    f32x4 o[4];
#pragma unroll
    for (int df = 0; df < 4; df++) o[df] = (f32x4){0.f, 0.f, 0.f, 0.f};
#pragma unroll
    for (int ks = 0; ks < 2; ks++) {
        short8 aa = *reinterpret_cast<const short8*>(&Ab[srow + frow][ks * 32 + fk]);
        short8 qa = *reinterpret_cast<const short8*>(&Qs[srow + frow][ks * 32 + fk]);
#pragma unroll
        for (int df = 0; df < 4; df++) {
            short8 vb = *reinterpret_cast<const short8*>(&VT[df * 16 + frow][ks * 32 + fk]);
            short8 sp = *reinterpret_cast<const short8*>(&SpT[df * 16 + frow][ks * 32 + fk]);
            o[df] = __builtin_amdgcn_mfma_f32_16x16x32_bf16(aa, vb, o[df], 0, 0, 0);
            o[df] = __builtin_amdgcn_mfma_f32_16x16x32_bf16(qa, sp, o[df], 0, 0, 0);
        }
    }

    // divide + scrambled bf16 store
    float inv[4];
    size_t obase[4];
#pragma unroll
    for (int r = 0; r < 4; r++) {
        int s_loc = srow + grp * 4 + r;
        float dq = dqz4[s_loc][0] + dqz4[s_loc][1] + dqz4[s_loc][2] + dqz4[s_loc][3];
        inv[r] = 1.f / (dq + dAS[s_loc] + EPS_);
        int s_b = c * 64 + s_loc;
        int jj  = n * S_ + s_b;
        obase[r] = (size_t)(b * S_ + (jj >> 3)) * 512 + (size_t)(jj & 7) * 64;
    }
#pragma unroll
    for (int df = 0; df < 4; df++) {
        int d = df * 16 + frow;
#pragma unroll
        for (int r = 0; r < 4; r++)
            av[obase[r] + d] = f2bf(o[df][r] * inv[r]);
    }
}

// ---------------------------------------------------------------------------
extern "C" void kernel_launch(void* const* d_in, const int* in_sizes, int n_in,
                              void* d_out, int out_size, void* d_ws, size_t ws_size,
                              hipStream_t stream)
{
    const float* q_in = (const float*)d_in[0];
    const float* k_in = (const float*)d_in[1];
    const float* v_in = (const float*)d_in[2];
    const float* wq   = (const float*)d_in[3];
    const float* bq   = (const float*)d_in[4];
    const float* wk   = (const float*)d_in[5];
    const float* bk   = (const float*)d_in[6];
    const float* wv   = (const float*)d_in[7];
    const float* bv   = (const float*)d_in[8];
    const float* wo   = (const float*)d_in[9];
    const float* bo   = (const float*)d_in[10];
    float* out = (float*)d_out;

    const size_t PLANE = (size_t)BS_ * 512;   // 2,097,152 elems

    float* ws = (float*)d_ws;
    float* Mb   = ws;                         // PLANE f32
    float* zbuf = Mb + PLANE;                 // 32768 f32
    unsigned short* u16 = (unsigned short*)(zbuf + 32768);
    unsigned short* pq  = u16;                // PLANE each
    unsigned short* pk  = pq  + PLANE;
    unsigned short* pkT = pk  + PLANE;
    unsigned short* pvT = pkT + PLANE;
    unsigned short* avb = pvT + PLANE;
    unsigned short* wqt = avb + PLANE;        // 262144 each
    unsigned short* wkt = wqt + 262144;
    unsigned short* wvt = wkt + 262144;
    unsigned short* wot = wvt + 262144;

    convert_wt_kernel<<<dim3(8, 8, 4), 256, 0, stream>>>(wq, wk, wv, wo, wqt, wkt, wvt, wot);
    qkv_proj_kernel<<<dim3(8, 32, 3), 256, 0, stream>>>(
        q_in, k_in, v_in, wqt, wkt, wvt, bq, bk, bv, pq, pk, pkT, pvT);
    chunk_kvscan_kernel<<<dim3(16, NBN), 256, 0, stream>>>(pkT, pvT, Mb, zbuf);
    chunk_attn_kernel<<<dim3(NCH, NBN), 256, 0, stream>>>(pq, pk, pvT, Mb, zbuf, avb);
    out_proj_kernel<<<dim3(8, 32), 256, 0, stream>>>(avb, wot, bo, out);
}

// Round 7
// 146.395 us; speedup vs baseline: 1.9172x; 1.0614x over previous
//
#include <hip/hip_runtime.h>
#include <hip/hip_bf16.h>
#include <cstdint>

// Problem constants
#define B_    2
#define S_    2048
#define H_    512
#define N_    8
#define D_    64
#define BS_   4096      // B*S
#define CHUNK 64
#define NCH   32        // S_/CHUNK
#define NBN   16        // B*N
#define EPS_  1e-6f

typedef __attribute__((ext_vector_type(4))) float  f32x4;
typedef __attribute__((ext_vector_type(8))) short  short8;
typedef __attribute__((ext_vector_type(4))) short  short4_t;

static __device__ __forceinline__ unsigned short f2bf(float x) {
    __hip_bfloat16 h = __float2bfloat16(x);
    return *reinterpret_cast<unsigned short*>(&h);
}
static __device__ __forceinline__ float bf2f(unsigned short u) {
    unsigned int v = ((unsigned int)u) << 16;
    float f;
    __builtin_memcpy(&f, &v, 4);
    return f;
}

// ---------------------------------------------------------------------------
// K0b: weight transpose+convert: Wt[c][k] = bf16(W[k][c]).  grid (8,8,4)
// ---------------------------------------------------------------------------
__global__ __launch_bounds__(256) void convert_wt_kernel(
    const float* __restrict__ wq, const float* __restrict__ wk,
    const float* __restrict__ wv, const float* __restrict__ wo,
    unsigned short* __restrict__ wqt, unsigned short* __restrict__ wkt,
    unsigned short* __restrict__ wvt, unsigned short* __restrict__ wot)
{
    const int m = blockIdx.z;
    const float* W = (m == 0) ? wq : (m == 1) ? wk : (m == 2) ? wv : wo;
    unsigned short* Wt = (m == 0) ? wqt : (m == 1) ? wkt : (m == 2) ? wvt : wot;

    __shared__ float t[64][65];
    const int k0 = blockIdx.y * 64, c0 = blockIdx.x * 64;
    const int tid = threadIdx.x;
    const int rr = tid >> 6;
    const int cc = tid & 63;
#pragma unroll
    for (int p = 0; p < 16; p++) {
        int kl = rr + p * 4;
        t[kl][cc] = W[(size_t)(k0 + kl) * 512 + c0 + cc];
    }
    __syncthreads();
#pragma unroll
    for (int p = 0; p < 16; p++) {
        int cl = rr + p * 4;
        Wt[(size_t)(c0 + cl) * 512 + k0 + cc] = f2bf(t[cc][cl]);
    }
}

// ---------------------------------------------------------------------------
// MFMA GEMM body, 128x64 tile, BK=64, 256 thr (4 waves as 2x2 -> 64x32 each).
// LDS is passed in from the caller so multiple template instantiations in one
// kernel SHARE the same allocation (was 3x82944 LDS -> 1 block/CU bug).
// MODE 0: phi, bf16 row-major out        (Q, f32 X)
// MODE 1: phi, bf16 row-major + [col][t] transposed out   (K, f32 X)
// MODE 2: no phi, transposed out only    (V, f32 X)
// MODE 3: no phi, f32 row-major out      (out-proj, bf16 X)
// ---------------------------------------------------------------------------
template<int MODE>
__device__ __forceinline__ void mfma_gemm_body(
    unsigned short (* __restrict__ As)[72], unsigned short (* __restrict__ Bs)[72],
    const void* __restrict__ Xv, const unsigned short* __restrict__ Wt,
    const float* __restrict__ bias,
    unsigned short* __restrict__ Obf, unsigned short* __restrict__ Ot,
    float* __restrict__ Of)
{
    const int tid  = threadIdx.x;
    const int lane = tid & 63;
    const int w    = tid >> 6;
    const int wm   = (w & 1) * 64;
    const int wn   = (w >> 1) * 32;
    const int row0 = blockIdx.y * 128;
    const int col0 = blockIdx.x * 64;
    const int frow = lane & 15;
    const int fk   = (lane >> 4) * 8;

    f32x4 acc[4][2];
#pragma unroll
    for (int m = 0; m < 4; m++)
#pragma unroll
        for (int n = 0; n < 2; n++) acc[m][n] = (f32x4){0.f, 0.f, 0.f, 0.f};

    const int lr = tid >> 3;          // 0..31
    const int lc = (tid & 7) * 8;     // 0..56

    for (int k0 = 0; k0 < 512; k0 += 64) {
        // A tile 128x64
#pragma unroll
        for (int p = 0; p < 4; p++) {
            int r = lr + p * 32;
            if (MODE == 3) {
                const unsigned short* X = (const unsigned short*)Xv;
                *reinterpret_cast<short8*>(&As[r][lc]) =
                    *reinterpret_cast<const short8*>(X + (size_t)(row0 + r) * 512 + k0 + lc);
            } else {
                const float* X = (const float*)Xv;
                const float* src = X + (size_t)(row0 + r) * 512 + k0 + lc;
                float4 x0 = *reinterpret_cast<const float4*>(src);
                float4 x1 = *reinterpret_cast<const float4*>(src + 4);
                short8 o;
                o[0] = (short)f2bf(x0.x); o[1] = (short)f2bf(x0.y);
                o[2] = (short)f2bf(x0.z); o[3] = (short)f2bf(x0.w);
                o[4] = (short)f2bf(x1.x); o[5] = (short)f2bf(x1.y);
                o[6] = (short)f2bf(x1.z); o[7] = (short)f2bf(x1.w);
                *reinterpret_cast<short8*>(&As[r][lc]) = o;
            }
        }
        // B tile 64x64
#pragma unroll
        for (int p = 0; p < 2; p++) {
            int r = (tid >> 3) + p * 32;
            *reinterpret_cast<short8*>(&Bs[r][lc]) =
                *reinterpret_cast<const short8*>(Wt + (size_t)(col0 + r) * 512 + k0 + lc);
        }
        __syncthreads();
#pragma unroll
        for (int kk = 0; kk < 64; kk += 32) {
            short8 a[4], b[2];
#pragma unroll
            for (int m = 0; m < 4; m++)
                a[m] = *reinterpret_cast<const short8*>(&As[wm + m * 16 + frow][kk + fk]);
#pragma unroll
            for (int n = 0; n < 2; n++)
                b[n] = *reinterpret_cast<const short8*>(&Bs[wn + n * 16 + frow][kk + fk]);
#pragma unroll
            for (int m = 0; m < 4; m++)
#pragma unroll
                for (int n = 0; n < 2; n++)
                    acc[m][n] = __builtin_amdgcn_mfma_f32_16x16x32_bf16(
                        a[m], b[n], acc[m][n], 0, 0, 0);
        }
        __syncthreads();
    }

    // Epilogue. C/D: col=lane&15, row=(lane>>4)*4+r (m89-verified)
#pragma unroll
    for (int n = 0; n < 2; n++) {
        int col = col0 + wn + n * 16 + frow;
        float bv_ = bias[col];
#pragma unroll
        for (int m = 0; m < 4; m++) {
            int rbase = row0 + wm + m * 16 + (lane >> 4) * 4;
            short4_t t4;
#pragma unroll
            for (int r = 0; r < 4; r++) {
                float val = acc[m][n][r] + bv_;
                if (MODE == 0 || MODE == 1)
                    val = (val > 0.f) ? (val + 1.f) : __expf(val);   // elu+1
                if (MODE == 3) {
                    Of[(size_t)(rbase + r) * 512 + col] = val;
                } else {
                    unsigned short ub = f2bf(val);
                    t4[r] = (short)ub;
                    if (MODE == 0 || MODE == 1)
                        Obf[(size_t)(rbase + r) * 512 + col] = ub;
                }
            }
            if (MODE == 1 || MODE == 2) {
                int bb = rbase >> 11;          // batch
                int t_ = rbase & 2047;         // time within batch
                *reinterpret_cast<short4_t*>(
                    Ot + (size_t)bb * (512 * 2048) + (size_t)col * 2048 + t_) = t4;
            }
        }
    }
}

// K1: QKV projections from f32 inputs. grid (8, 32, 3), block 256
__global__ __launch_bounds__(256, 4) void qkv_proj_kernel(
    const float* __restrict__ q_in, const float* __restrict__ k_in,
    const float* __restrict__ v_in,
    const unsigned short* __restrict__ wqt, const unsigned short* __restrict__ wkt,
    const unsigned short* __restrict__ wvt,
    const float* __restrict__ bq, const float* __restrict__ bk, const float* __restrict__ bv,
    unsigned short* __restrict__ pq, unsigned short* __restrict__ pk,
    unsigned short* __restrict__ pkT, unsigned short* __restrict__ pvT)
{
    __shared__ unsigned short As[128][72];
    __shared__ unsigned short Bs[64][72];
    int m = blockIdx.z;
    if (m == 0)      mfma_gemm_body<0>(As, Bs, q_in, wqt, bq, pq, nullptr, nullptr);
    else if (m == 1) mfma_gemm_body<1>(As, Bs, k_in, wkt, bk, pk, pkT, nullptr);
    else             mfma_gemm_body<2>(As, Bs, v_in, wvt, bv, nullptr, pvT, nullptr);
}

// K5: output projection. grid (8, 32), block 256
__global__ __launch_bounds__(256, 4) void out_proj_kernel(
    const unsigned short* __restrict__ avb, const unsigned short* __restrict__ wot,
    const float* __restrict__ bo, float* __restrict__ out)
{
    __shared__ unsigned short As[128][72];
    __shared__ unsigned short Bs[64][72];
    mfma_gemm_body<3>(As, Bs, avb, wot, bo, nullptr, nullptr, out);
}

// ---------------------------------------------------------------------------
// K23 (fused chunk-KV + exclusive scan):
//   M'_c[d][h] = sum_{t in chunk c} V[t,d]*K[t,h];  Mb[bn][c] = exclusive prefix (bf16)
//   z_c[h] = sum_t K[t,h];                          zb[bn][c] = exclusive prefix (f32)
// grid (16, 16): x = (dblk<<2)|hblk tile of 16x16, y = bn. block 256 (4 waves).
// ---------------------------------------------------------------------------
__global__ __launch_bounds__(256) void chunk_kvscan_kernel(
    const unsigned short* __restrict__ pkT, const unsigned short* __restrict__ pvT,
    unsigned short* __restrict__ Mb, float* __restrict__ zb)
{
    __shared__ float waveTot[4][256];     // per-wave state totals
    __shared__ float zTot[4][16];         // per-wave z totals

    const int tile = blockIdx.x;
    const int bn   = blockIdx.y;
    const int d0   = (tile >> 2) * 16;
    const int h0   = (tile & 3) * 16;
    const int b = bn >> 3, n = bn & 7;
    const int tid = threadIdx.x, lane = tid & 63, w = tid >> 6;
    const int frow = lane & 15, grp = lane >> 4, fk = grp * 8;
    const bool do_z = (tile >> 2) == 0;

    const size_t vrow = (size_t)b * (512 * 2048) + (size_t)(n * 64 + d0 + frow) * 2048;
    const size_t krow = (size_t)b * (512 * 2048) + (size_t)(n * 64 + h0 + frow) * 2048;

    f32x4 run = (f32x4){0.f, 0.f, 0.f, 0.f};
    f32x4 loc[8];
    float runz = 0.f, locz[8];

#pragma unroll
    for (int c = 0; c < 8; c++) {
        int t0 = (w * 8 + c) * 64;
        loc[c] = run;
        locz[c] = runz;
        short8 a0 = *reinterpret_cast<const short8*>(pvT + vrow + t0 + fk);
        short8 a1 = *reinterpret_cast<const short8*>(pvT + vrow + t0 + 32 + fk);
        short8 b0 = *reinterpret_cast<const short8*>(pkT + krow + t0 + fk);
        short8 b1 = *reinterpret_cast<const short8*>(pkT + krow + t0 + 32 + fk);
        run = __builtin_amdgcn_mfma_f32_16x16x32_bf16(a0, b0, run, 0, 0, 0);
        run = __builtin_amdgcn_mfma_f32_16x16x32_bf16(a1, b1, run, 0, 0, 0);
        if (do_z) {
            float zp = 0.f;
#pragma unroll
            for (int j = 0; j < 8; j++) zp += bf2f((unsigned short)b0[j]) + bf2f((unsigned short)b1[j]);
            zp += __shfl_xor(zp, 16);
            zp += __shfl_xor(zp, 32);
            runz += zp;
        }
    }

    // publish wave totals
#pragma unroll
    for (int r = 0; r < 4; r++)
        waveTot[w][(grp * 4 + r) * 16 + frow] = run[r];
    if (do_z && lane < 16) zTot[w][frow] = runz;
    __syncthreads();

    // carry = sum of totals of preceding waves
    f32x4 carry = (f32x4){0.f, 0.f, 0.f, 0.f};
    float carryz = 0.f;
    for (int pw = 0; pw < w; pw++) {
#pragma unroll
        for (int r = 0; r < 4; r++)
            carry[r] += waveTot[pw][(grp * 4 + r) * 16 + frow];
        carryz += zTot[pw][frow];
    }

    // store exclusive prefixes (state as bf16)
#pragma unroll
    for (int c = 0; c < 8; c++) {
        size_t mbase = ((size_t)bn * NCH + (w * 8 + c)) * 4096;
#pragma unroll
        for (int r = 0; r < 4; r++)
            Mb[mbase + (size_t)(d0 + grp * 4 + r) * 64 + h0 + frow] = f2bf(carry[r] + loc[c][r]);
        if (do_z && lane < 16)
            zb[((size_t)bn * NCH + (w * 8 + c)) * 64 + h0 + frow] = carryz + locz[c];
    }
}

// ---------------------------------------------------------------------------
// K4 (MFMA): per-chunk attention.
//   A = tril(Q K^T); O = A V + Q Sp'; denom = qz_prev + rowsum(A) + eps
//   av = O/denom stored bf16 in reference's scrambled reshape layout.
// grid (NCH, NBN), block 256 (4 waves; wave w owns rows w*16..w*16+15)
// ---------------------------------------------------------------------------
__global__ __launch_bounds__(256) void chunk_attn_kernel(
    const unsigned short* __restrict__ pq, const unsigned short* __restrict__ pk,
    const unsigned short* __restrict__ pvT, const unsigned short* __restrict__ Mb,
    const float* __restrict__ zb, unsigned short* __restrict__ av)
{
    __shared__ unsigned short Qs[64][72], Ks[64][72], VT[64][72], SpT[64][72], Ab[64][72];
    __shared__ float zs[64], dqz4[64][4], dAS[64];

    const int c = blockIdx.x, bn = blockIdx.y;
    const int b = bn >> 3, n = bn & 7;
    const int row0 = b * S_ + c * 64;
    const int col0 = n * 64;
    const int t0 = c * 64;
    const size_t vbase = (size_t)b * 512 * 2048;
    const size_t mbase = ((size_t)bn * NCH + c) * 4096;
    const int tid = threadIdx.x, lane = tid & 63, w = tid >> 6;

    // stage (all bf16, straight short8 copies)
#pragma unroll
    for (int p = 0; p < 2; p++) {
        int r  = (tid >> 3) + p * 32;
        int c8 = (tid & 7) * 8;
        *reinterpret_cast<short8*>(&Qs[r][c8]) =
            *reinterpret_cast<const short8*>(pq + (size_t)(row0 + r) * 512 + col0 + c8);
        *reinterpret_cast<short8*>(&Ks[r][c8]) =
            *reinterpret_cast<const short8*>(pk + (size_t)(row0 + r) * 512 + col0 + c8);
        *reinterpret_cast<short8*>(&VT[r][c8]) =
            *reinterpret_cast<const short8*>(pvT + vbase + (size_t)(col0 + r) * 2048 + t0 + c8);
        *reinterpret_cast<short8*>(&SpT[r][c8]) =
            *reinterpret_cast<const short8*>(Mb + mbase + (size_t)r * 64 + c8);
    }
    if (tid < 64) zs[tid] = zb[((size_t)bn * NCH + c) * 64 + tid];
    __syncthreads();

    const int frow = lane & 15, grp = lane >> 4, fk = grp * 8;
    const int srow = w * 16;

    // QK^T
    f32x4 a1[4];
#pragma unroll
    for (int tf = 0; tf < 4; tf++) a1[tf] = (f32x4){0.f, 0.f, 0.f, 0.f};
#pragma unroll
    for (int ks = 0; ks < 2; ks++) {
        short8 qa = *reinterpret_cast<const short8*>(&Qs[srow + frow][ks * 32 + fk]);
#pragma unroll
        for (int tf = 0; tf < 4; tf++) {
            short8 kb = *reinterpret_cast<const short8*>(&Ks[tf * 16 + frow][ks * 32 + fk]);
            a1[tf] = __builtin_amdgcn_mfma_f32_16x16x32_bf16(qa, kb, a1[tf], 0, 0, 0);
        }
    }

    // mask + rowsum + Ab
    float rs[4] = {0.f, 0.f, 0.f, 0.f};
#pragma unroll
    for (int tf = 0; tf < 4; tf++) {
        int t_ = tf * 16 + frow;
#pragma unroll
        for (int r = 0; r < 4; r++) {
            int s_ = srow + grp * 4 + r;
            float v = (t_ <= s_) ? a1[tf][r] : 0.f;
            rs[r] += v;
            Ab[s_][t_] = f2bf(v);
        }
    }
#pragma unroll
    for (int msk = 1; msk < 16; msk <<= 1)
#pragma unroll
        for (int r = 0; r < 4; r++) rs[r] += __shfl_xor(rs[r], msk);
    if (frow == 0) {
#pragma unroll
        for (int r = 0; r < 4; r++) dAS[srow + grp * 4 + r] = rs[r];
    }

    // q·z_prev, split across all 256 threads (16 MACs each)
    {
        int s = tid & 63, part = tid >> 6;
        float sdq = 0.f;
#pragma unroll
        for (int j = 0; j < 16; j++) {
            int h = part * 16 + j;
            sdq += bf2f(Qs[s][h]) * zs[h];
        }
        dqz4[s][part] = sdq;
    }
    __syncthreads();

    // O = A V + Q Sp'
    f32x4 o[4];
#pragma unroll
    for (int df = 0; df < 4; df++) o[df] = (f32x4){0.f, 0.f, 0.f, 0.f};
#pragma unroll
    for (int ks = 0; ks < 2; ks++) {
        short8 aa = *reinterpret_cast<const short8*>(&Ab[srow + frow][ks * 32 + fk]);
        short8 qa = *reinterpret_cast<const short8*>(&Qs[srow + frow][ks * 32 + fk]);
#pragma unroll
        for (int df = 0; df < 4; df++) {
            short8 vb = *reinterpret_cast<const short8*>(&VT[df * 16 + frow][ks * 32 + fk]);
            short8 sp = *reinterpret_cast<const short8*>(&SpT[df * 16 + frow][ks * 32 + fk]);
            o[df] = __builtin_amdgcn_mfma_f32_16x16x32_bf16(aa, vb, o[df], 0, 0, 0);
            o[df] = __builtin_amdgcn_mfma_f32_16x16x32_bf16(qa, sp, o[df], 0, 0, 0);
        }
    }

    // divide + scrambled bf16 store
    float inv[4];
    size_t obase[4];
#pragma unroll
    for (int r = 0; r < 4; r++) {
        int s_loc = srow + grp * 4 + r;
        float dq = dqz4[s_loc][0] + dqz4[s_loc][1] + dqz4[s_loc][2] + dqz4[s_loc][3];
        inv[r] = 1.f / (dq + dAS[s_loc] + EPS_);
        int s_b = c * 64 + s_loc;
        int jj  = n * S_ + s_b;
        obase[r] = (size_t)(b * S_ + (jj >> 3)) * 512 + (size_t)(jj & 7) * 64;
    }
#pragma unroll
    for (int df = 0; df < 4; df++) {
        int d = df * 16 + frow;
#pragma unroll
        for (int r = 0; r < 4; r++)
            av[obase[r] + d] = f2bf(o[df][r] * inv[r]);
    }
}

// ---------------------------------------------------------------------------
extern "C" void kernel_launch(void* const* d_in, const int* in_sizes, int n_in,
                              void* d_out, int out_size, void* d_ws, size_t ws_size,
                              hipStream_t stream)
{
    const float* q_in = (const float*)d_in[0];
    const float* k_in = (const float*)d_in[1];
    const float* v_in = (const float*)d_in[2];
    const float* wq   = (const float*)d_in[3];
    const float* bq   = (const float*)d_in[4];
    const float* wk   = (const float*)d_in[5];
    const float* bk   = (const float*)d_in[6];
    const float* wv   = (const float*)d_in[7];
    const float* bv   = (const float*)d_in[8];
    const float* wo   = (const float*)d_in[9];
    const float* bo   = (const float*)d_in[10];
    float* out = (float*)d_out;

    const size_t PLANE = (size_t)BS_ * 512;   // 2,097,152 elems

    float* ws = (float*)d_ws;
    float* zbuf = ws;                         // 32768 f32
    unsigned short* u16 = (unsigned short*)(zbuf + 32768);
    unsigned short* Mb  = u16;                // PLANE bf16
    unsigned short* pq  = Mb  + PLANE;        // PLANE each
    unsigned short* pk  = pq  + PLANE;
    unsigned short* pkT = pk  + PLANE;
    unsigned short* pvT = pkT + PLANE;
    unsigned short* avb = pvT + PLANE;
    unsigned short* wqt = avb + PLANE;        // 262144 each
    unsigned short* wkt = wqt + 262144;
    unsigned short* wvt = wkt + 262144;
    unsigned short* wot = wvt + 262144;

    convert_wt_kernel<<<dim3(8, 8, 4), 256, 0, stream>>>(wq, wk, wv, wo, wqt, wkt, wvt, wot);
    qkv_proj_kernel<<<dim3(8, 32, 3), 256, 0, stream>>>(
        q_in, k_in, v_in, wqt, wkt, wvt, bq, bk, bv, pq, pk, pkT, pvT);
    chunk_kvscan_kernel<<<dim3(16, NBN), 256, 0, stream>>>(pkT, pvT, Mb, zbuf);
    chunk_attn_kernel<<<dim3(NCH, NBN), 256, 0, stream>>>(pq, pk, pvT, Mb, zbuf, avb);
    out_proj_kernel<<<dim3(8, 32), 256, 0, stream>>>(avb, wot, bo, out);
}